// Round 10
// baseline (1983.897 us; speedup 1.0000x reference)
//
#include <hip/hip_runtime.h>

#define HD 64
#define BT 16          // batch tile per block
#define L2E 1.4426950408889634f

typedef _Float16 v8h __attribute__((ext_vector_type(8)));
typedef _Float16 v2h __attribute__((ext_vector_type(2)));
typedef float    v4f __attribute__((ext_vector_type(4)));

__device__ __forceinline__ float fexp2(float x) { return __builtin_amdgcn_exp2f(x); }
__device__ __forceinline__ float frcp(float x)  { return __builtin_amdgcn_rcpf(x); }
__device__ __forceinline__ float fsig(float x)  { return frcp(fexp2(-L2E * x) + 1.f); }
__device__ __forceinline__ float ftanh_fast(float x) {
    return 1.f - 2.f * frcp(fexp2(2.f * L2E * x) + 1.f);
}

#define MFMA16(A, Bf, C) __builtin_amdgcn_mfma_f32_16x16x32_f16((A), (Bf), (C), 0, 0, 0)

// pack two f32 -> v2h (RTZ), bit-cast around the __fp16 return type
__device__ __forceinline__ v2h pk2h(float a, float b) {
    return __builtin_bit_cast(v2h, __builtin_amdgcn_cvt_pkrtz(a, b));
}

// load 8 consecutive f32 -> v8h (f16)
__device__ __forceinline__ v8h cvt8(const float* p) {
    float4 a = ((const float4*)p)[0];
    float4 b = ((const float4*)p)[1];
    v8h r;
    r[0]=(_Float16)a.x; r[1]=(_Float16)a.y; r[2]=(_Float16)a.z; r[3]=(_Float16)a.w;
    r[4]=(_Float16)b.x; r[5]=(_Float16)b.y; r[6]=(_Float16)b.z; r[7]=(_Float16)b.w;
    return r;
}

// One block per 16 batch elements (grid = B/16). 512 threads = 8 waves.
// Per step: gates = W(256x64) . h^T(64x16) via mfma_f32_16x16x32_f16
// (M-tile=16 gate rows, N=16 batch, K=64 in 2 chunks). Wave m owns units
// 8m..8m+7 through 2 M-tiles with unit interleave u(tile,ul)=8m+2*ul+tile,
// rows permuted as mlocal=4*ul+gate so a lane's 4 C-regs are the 4 gates of
// one unit -> in-lane c/h update, h packed (cvt_pkrtz) -> one ds_write_b32.
// Wave m holds A-frags of Whh0/Wih1/Whh1 for its tiles; xproj C-tiles stay in
// registers (MFMA C-chaining, no LDS). h0/h1 live in LDS as f16 [n][unit]
// (stride 72: 16B-aligned, 2-way banks within quarter-wave = free).
// Lag pipeline (one barrier/iter, parity dbuf): iter i does gates0(t=i),
// xproj(t=i-1) [same h0(i-1) B-frags], gates1(t=i-2), head(t=i-3, wave 0).
__launch_bounds__(512, 1)
__global__ void lstm2_kernel(const float* __restrict__ x,     // [B,T]
                             const float* __restrict__ h0in,  // [2,B,HD]
                             const float* __restrict__ c0in,  // [2,B,HD]
                             const float* __restrict__ Wih0,  // [4H,1]
                             const float* __restrict__ Whh0,  // [4H,HD]
                             const float* __restrict__ bih0,
                             const float* __restrict__ bhh0,
                             const float* __restrict__ Wih1,  // [4H,HD]
                             const float* __restrict__ Whh1,  // [4H,HD]
                             const float* __restrict__ bih1,
                             const float* __restrict__ bhh1,
                             const float* __restrict__ Wlin,  // [1,HD]
                             const float* __restrict__ blin,  // [1]
                             float* __restrict__ out,         // [B,T]
                             int B, int T)
{
    const int bb   = blockIdx.x * BT;      // batch base
    const int tid  = threadIdx.x;
    const int m    = tid >> 6;             // wave 0..7
    const int lane = tid & 63;
    const int q    = lane >> 4;            // quad (C rows 4q..4q+3; B k-group)
    const int n    = lane & 15;            // batch column
    const int ulA  = (lane & 15) >> 2;     // A-operand roles
    const int gA   = (lane & 15) & 3;

    __shared__ __align__(16) _Float16 h0l[2][BT][72];  // [par][n][unit]
    __shared__ __align__(16) _Float16 h1l[2][BT][72];
    __shared__ float xl[2][BT][65];                    // staged x chunks

    // ---- zero all LDS (launch-history independence), barrier, then init ----
    { _Float16* p0 = &h0l[0][0][0]; _Float16* p1 = &h1l[0][0][0];
      for (int idx = tid; idx < 2 * BT * 72; idx += 512) { p0[idx] = (_Float16)0.f; p1[idx] = (_Float16)0.f; }
      float* px = &xl[0][0][0];
      for (int idx = tid; idx < 2 * BT * 65; idx += 512) px[idx] = 0.f; }
    __syncthreads();

    // ---- A-fragments: [tile][chunk], rows r = gA*64 + (8m + 2*ulA + tile) ----
    v8h wA[2][2], wB[2][2], wC[2][2];
    #pragma unroll
    for (int t = 0; t < 2; ++t) {
        const int r = gA * HD + (8 * m + 2 * ulA + t);
        #pragma unroll
        for (int c = 0; c < 2; ++c) {
            const int k0 = 32 * c + 8 * q;
            wA[t][c] = cvt8(Whh0 + r * HD + k0);
            wB[t][c] = cvt8(Wih1 + r * HD + k0);
            wC[t][c] = cvt8(Whh1 + r * HD + k0);
        }
    }

    // ---- consumer-side constants: unit u = 8m + 2q + t ----
    v4f b0v[2], wx0v[2], b1v[2];
    float c0s[2], c1s[2];
    #pragma unroll
    for (int t = 0; t < 2; ++t) {
        const int u = 8 * m + 2 * q + t;
        #pragma unroll
        for (int g = 0; g < 4; ++g) {
            const int r = g * HD + u;
            b0v[t][g]  = bih0[r] + bhh0[r];
            wx0v[t][g] = Wih0[r];
            b1v[t][g]  = bih1[r] + bhh1[r];
        }
        c0s[t] = c0in[(bb + n) * HD + u];
        c1s[t] = c0in[(size_t)B * HD + (bb + n) * HD + u];
    }
    {   // h state init into parity 1 (read at i=0 / i=2)
        const int u0 = 8 * m + 2 * q;
        *(v2h*)&h0l[1][n][u0] = pk2h(
            h0in[(bb + n) * HD + u0], h0in[(bb + n) * HD + u0 + 1]);
        *(v2h*)&h1l[1][n][u0] = pk2h(
            h0in[(size_t)B * HD + (bb + n) * HD + u0],
            h0in[(size_t)B * HD + (bb + n) * HD + u0 + 1]);
    }

    // head weights (wave 0 only): unit pairs 16q+2s
    v2h wlp[8];
    if (m == 0) {
        #pragma unroll
        for (int s = 0; s < 8; ++s)
            wlp[s] = v2h{(_Float16)Wlin[16 * q + 2 * s], (_Float16)Wlin[16 * q + 2 * s + 1]};
    }
    const float blin0 = blin[0];

    // preload x chunk 0
    for (int idx = tid; idx < BT * 64; idx += 512) {
        const int nn = idx >> 6, tt = idx & 63;
        xl[0][nn][tt] = x[(bb + nn) * T + tt];
    }

    v4f xp[2][2];                         // xproj C-tiles: [slot][tile]
    #pragma unroll
    for (int t = 0; t < 2; ++t) { xp[0][t] = v4f{0.f,0.f,0.f,0.f}; xp[1][t] = xp[0][t]; }

    for (int i = 0; i <= T + 2; ++i) {
        __syncthreads();

        // stage next x chunk (visible after next barrier)
        if (((i + 1) & 63) == 0 && (i + 1) < T) {
            const int ib = i + 1, buf = (ib >> 6) & 1;
            for (int idx = tid; idx < BT * 64; idx += 512) {
                const int nn = idx >> 6, tt = idx & 63;
                xl[buf][nn][tt] = x[(bb + nn) * T + ib + tt];
            }
        }

        const int pr = (i + 1) & 1;       // read parity (state from iter i-1)
        const int pw = i & 1;             // write parity

        if (i <= T) {                     // needs h0(i-1) B-frags
            const v8h f0c0 = *(const v8h*)&h0l[pr][n][8 * q];
            const v8h f0c1 = *(const v8h*)&h0l[pr][n][32 + 8 * q];

            if (i >= 1) {                 // xproj(t=i-1): C=bias1, D->slot pr
                #pragma unroll
                for (int t = 0; t < 2; ++t) {
                    v4f d = MFMA16(wB[t][0], f0c0, b1v[t]);
                    xp[pr][t] = MFMA16(wB[t][1], f0c1, d);
                }
            }
            if (i < T) {                  // gates0(t=i) + layer-0 update
                const float xv = xl[(i >> 6) & 1][n][i & 63];
                float hn[2];
                #pragma unroll
                for (int t = 0; t < 2; ++t) {
                    v4f ci;
                    #pragma unroll
                    for (int g = 0; g < 4; ++g) ci[g] = fmaf(wx0v[t][g], xv, b0v[t][g]);
                    v4f d = MFMA16(wA[t][0], f0c0, ci);
                    d = MFMA16(wA[t][1], f0c1, d);
                    const float si = fsig(d[0]), sf = fsig(d[1]);
                    const float tg = ftanh_fast(d[2]), so = fsig(d[3]);
                    c0s[t] = fmaf(sf, c0s[t], si * tg);
                    hn[t]  = so * ftanh_fast(c0s[t]);
                }
                *(v2h*)&h0l[pw][n][8 * m + 2 * q] = pk2h(hn[0], hn[1]);
            }
        }

        if (i >= 2 && i <= T + 1) {       // gates1(t=i-2): C = xp(t=i-2) = slot pw
            const v8h f1c0 = *(const v8h*)&h1l[pr][n][8 * q];
            const v8h f1c1 = *(const v8h*)&h1l[pr][n][32 + 8 * q];
            float hn[2];
            #pragma unroll
            for (int t = 0; t < 2; ++t) {
                v4f d = MFMA16(wC[t][0], f1c0, xp[pw][t]);
                d = MFMA16(wC[t][1], f1c1, d);
                const float si = fsig(d[0]), sf = fsig(d[1]);
                const float tg = ftanh_fast(d[2]), so = fsig(d[3]);
                c1s[t] = fmaf(sf, c1s[t], si * tg);
                hn[t]  = so * ftanh_fast(c1s[t]);
            }
            *(v2h*)&h1l[pw][n][8 * m + 2 * q] = pk2h(hn[0], hn[1]);
        }

        if (m == 0 && i >= 3) {           // head(t=i-3): h1l[pr] holds h1(i-3)
            const v2h* hp = (const v2h*)&h1l[pr][n][16 * q];
            float p = 0.f;
            #pragma unroll
            for (int s = 0; s < 8; ++s) p = __builtin_amdgcn_fdot2(wlp[s], hp[s], p, false);
            p += __shfl_xor(p, 16, 64);
            p += __shfl_xor(p, 32, 64);
            if (lane < 16) out[(bb + n) * T + (i - 3)] = p + blin0;
        }
    }
}

extern "C" void kernel_launch(void* const* d_in, const int* in_sizes, int n_in,
                              void* d_out, int out_size, void* d_ws, size_t ws_size,
                              hipStream_t stream)
{
    const float* x    = (const float*)d_in[0];
    const float* h0   = (const float*)d_in[1];
    const float* c0   = (const float*)d_in[2];
    const float* Wih0 = (const float*)d_in[3];
    const float* Whh0 = (const float*)d_in[4];
    const float* bih0 = (const float*)d_in[5];
    const float* bhh0 = (const float*)d_in[6];
    const float* Wih1 = (const float*)d_in[7];
    const float* Whh1 = (const float*)d_in[8];
    const float* bih1 = (const float*)d_in[9];
    const float* bhh1 = (const float*)d_in[10];
    const float* Wlin = (const float*)d_in[11];
    const float* blin = (const float*)d_in[12];
    float* out = (float*)d_out;

    const int B = in_sizes[1] / (2 * HD);   // h0 is [2,B,HD]
    const int T = in_sizes[0] / B;          // input is [B,T]

    lstm2_kernel<<<dim3(B / BT), dim3(512), 0, stream>>>(
        x, h0, c0, Wih0, Whh0, bih0, bhh0,
        Wih1, Whh1, bih1, bhh1, Wlin, blin, out, B, T);
}